// Round 4
// baseline (177.512 us; speedup 1.0000x reference)
//
#include <hip/hip_runtime.h>
#include <math.h>

#define TPB 256
#define TILE 128          // target points per split (one LDS tile per block)
#define PPT 2             // source points per thread
#define MAXCOL 64

// Device-global sync state: zero-initialized at module load, self-reset at the
// end of every launch (so each graph replay sees zeros; never in poisoned d_ws).
__device__ int   g_colcnt[MAXCOL];
__device__ int   g_fincnt;
__device__ float g_colsum[MAXCOL];

// Per-point loss: reduce S partials, loss chain, T-step discounted scan.
__device__ __forceinline__ float point_loss(
    const float4* __restrict__ part,
    const float* __restrict__ label,
    const float* __restrict__ path_m,
    const float* __restrict__ path_maxprob_m,
    int i, int N, int S, int T)
{
    float mins = 3.402823e38f, maxs = -3.402823e38f;
    float mine = 3.402823e38f, maxe = -3.402823e38f;
    #pragma unroll 4
    for (int s = 0; s < S; ++s) {
        const float4 v = part[(long)s * N + i];
        mins = fminf(mins, v.x); maxs = fmaxf(maxs, v.y);
        mine = fminf(mine, v.z); maxe = fmaxf(maxe, v.w);
    }
    const float p = 0.002f, L0 = 0.4f, lam = 0.05f, gamma = 0.99f;
    const float loss_start = 0.99f * mins + 0.01f * maxs;
    const float loss_end   = 0.99f * mine + 0.01f * maxe;
    const float loss_dt    = loss_end - loss_start;
    const float d = fminf(loss_end / L0, 1.0f);
    const float l = expf(-label[i]);
    const float reward_end = -p * path_m[(long)(T - 1) * N + i]
                             - (d + lam * l) * loss_dt;
    float R = 0.0f, L = 0.0f;
    for (int t = T - 1; t >= 0; --t) {
        const float r  = (t == T - 1) ? reward_end
                                      : (-p * path_m[(long)t * N + i]);
        const float lp = logf(path_maxprob_m[(long)t * N + i]);
        R = gamma * R + lp * (r + 0.02f);
        L -= R;
    }
    return L / (float)T;
}

// Fused single kernel.
// grid = (NB, S); block (bx, s): source points [bx*512, bx*512+512) (2/thread)
// vs target split s (TILE targets), dot-product form with |t|^2 in LDS.
// part layout: [S][N] float4 {min_start, max_start, min_end, max_end}.
// The 64th block to finish column bx (device-scope counter + fences) runs
// phase B for that column's 512 points; the 16th finisher writes the mean.
__global__ __launch_bounds__(TPB) void fused_reward(
    const float* __restrict__ source,
    const float* __restrict__ target,
    const float* __restrict__ label,
    const float* __restrict__ trans_m,
    const float* __restrict__ path_m,
    const float* __restrict__ path_maxprob_m,
    float4* __restrict__ part,
    float* __restrict__ out,
    int N, int M, int T, int S, int NB)
{
    const int bx  = blockIdx.x;   // column
    const int s   = blockIdx.y;   // target split
    const int tid = threadIdx.x;

    __shared__ float4 tgt[TILE];

    // ---- stage this block's single target tile as {x,y,z,|t|^2} ----
    if (tid < TILE) {
        const long j = (long)s * TILE + tid;
        const float tx = target[j * 3 + 0];
        const float ty = target[j * 3 + 1];
        const float tz = target[j * 3 + 2];
        tgt[tid] = make_float4(tx, ty, tz, fmaf(tx, tx, fmaf(ty, ty, tz * tz)));
    }

    // ---- two source points per thread ----
    const int i0 = bx * (PPT * TPB) + tid;
    const int i1 = i0 + TPB;

    float sx0 = source[i0 * 3 + 0], sy0 = source[i0 * 3 + 1], sz0 = source[i0 * 3 + 2];
    float sx1 = source[i1 * 3 + 0], sy1 = source[i1 * 3 + 1], sz1 = source[i1 * 3 + 2];
    const long te = (long)(T - 1) * N * 3;
    const float ex0 = sx0 - trans_m[te + (long)i0 * 3 + 0];
    const float ey0 = sy0 - trans_m[te + (long)i0 * 3 + 1];
    const float ez0 = sz0 - trans_m[te + (long)i0 * 3 + 2];
    const float ex1 = sx1 - trans_m[te + (long)i1 * 3 + 0];
    const float ey1 = sy1 - trans_m[te + (long)i1 * 3 + 1];
    const float ez1 = sz1 - trans_m[te + (long)i1 * 3 + 2];

    const float ss0 = fmaf(sx0, sx0, fmaf(sy0, sy0, sz0 * sz0));
    const float ss1 = fmaf(sx1, sx1, fmaf(sy1, sy1, sz1 * sz1));
    const float ee0 = fmaf(ex0, ex0, fmaf(ey0, ey0, ez0 * ez0));
    const float ee1 = fmaf(ex1, ex1, fmaf(ey1, ey1, ez1 * ez1));
    // -2x factors folded into dot
    sx0 *= -2.0f; sy0 *= -2.0f; sz0 *= -2.0f;
    sx1 *= -2.0f; sy1 *= -2.0f; sz1 *= -2.0f;
    const float fx0 = -2.0f * ex0, fy0 = -2.0f * ey0, fz0 = -2.0f * ez0;
    const float fx1 = -2.0f * ex1, fy1 = -2.0f * ey1, fz1 = -2.0f * ez1;

    float mn_s0 = 3.402823e38f, mx_s0 = -3.402823e38f;
    float mn_e0 = 3.402823e38f, mx_e0 = -3.402823e38f;
    float mn_s1 = 3.402823e38f, mx_s1 = -3.402823e38f;
    float mn_e1 = 3.402823e38f, mx_e1 = -3.402823e38f;

    __syncthreads();

    #pragma unroll 8
    for (int j = 0; j < TILE; ++j) {
        const float4 t = tgt[j];
        float a0 = fmaf(sx0, t.x, t.w); a0 = fmaf(sy0, t.y, a0); a0 = fmaf(sz0, t.z, a0);
        mn_s0 = fminf(mn_s0, a0); mx_s0 = fmaxf(mx_s0, a0);
        float b0 = fmaf(fx0, t.x, t.w); b0 = fmaf(fy0, t.y, b0); b0 = fmaf(fz0, t.z, b0);
        mn_e0 = fminf(mn_e0, b0); mx_e0 = fmaxf(mx_e0, b0);
        float a1 = fmaf(sx1, t.x, t.w); a1 = fmaf(sy1, t.y, a1); a1 = fmaf(sz1, t.z, a1);
        mn_s1 = fminf(mn_s1, a1); mx_s1 = fmaxf(mx_s1, a1);
        float b1 = fmaf(fx1, t.x, t.w); b1 = fmaf(fy1, t.y, b1); b1 = fmaf(fz1, t.z, b1);
        mn_e1 = fminf(mn_e1, b1); mx_e1 = fmaxf(mx_e1, b1);
    }

    part[(long)s * N + i0] = make_float4(mn_s0 + ss0, mx_s0 + ss0, mn_e0 + ee0, mx_e0 + ee0);
    part[(long)s * N + i1] = make_float4(mn_s1 + ss1, mx_s1 + ss1, mn_e1 + ee1, mx_e1 + ee1);

    // ---- column completion counter (device-scope) ----
    __threadfence();                    // publish partials device-wide
    __shared__ int s_old;
    if (tid == 0) s_old = atomicAdd(&g_colcnt[bx], 1);
    __syncthreads();
    if (s_old != S - 1) return;         // not the last block of this column
    if (tid == 0) g_colcnt[bx] = 0;     // self-reset (all S adds complete)
    __threadfence();                    // acquire: order partial reads below

    // ---- phase B: this block reduces its column's 512 points ----
    float v = point_loss(part, label, path_m, path_maxprob_m, i0, N, S, T)
            + point_loss(part, label, path_m, path_maxprob_m, i1, N, S, T);

    // block reduction (4 waves of 64), fixed order -> deterministic
    for (int off = 32; off > 0; off >>= 1) v += __shfl_down(v, off, 64);
    __shared__ float red[TPB / 64];
    const int wid = tid >> 6, lane = tid & 63;
    if (lane == 0) red[wid] = v;
    __syncthreads();
    if (tid == 0) {
        float csum = 0.0f;
        #pragma unroll
        for (int w = 0; w < TPB / 64; ++w) csum += red[w];
        g_colsum[bx] = csum;
        __threadfence();                // publish colsum
        const int o2 = atomicAdd(&g_fincnt, 1);
        if (o2 == NB - 1) {             // last column done -> final sum
            g_fincnt = 0;               // self-reset
            __threadfence();            // acquire colsums
            float tot = 0.0f;
            for (int b = 0; b < NB; ++b)
                tot += ((volatile float*)g_colsum)[b];
            out[0] = tot / (float)N;
        }
    }
}

extern "C" void kernel_launch(void* const* d_in, const int* in_sizes, int n_in,
                              void* d_out, int out_size, void* d_ws, size_t ws_size,
                              hipStream_t stream) {
    const float* source = (const float*)d_in[0];
    const float* target = (const float*)d_in[1];
    const float* label  = (const float*)d_in[2];
    const float* trans  = (const float*)d_in[3];
    const float* path   = (const float*)d_in[4];
    const float* pmax   = (const float*)d_in[5];

    const int N = in_sizes[0] / 3;          // 8192
    const int M = in_sizes[1] / 3;          // 8192
    const int T = in_sizes[3] / (N * 3);    // 8
    const int S  = M / TILE;                // 64 splits
    const int NB = N / (PPT * TPB);         // 16 columns

    float4* part = (float4*)d_ws;           // [S][N] float4 (8 MB)

    fused_reward<<<dim3(NB, S), TPB, 0, stream>>>(
        source, target, label, trans, path, pmax,
        part, (float*)d_out, N, M, T, S, NB);
}

// Round 5
// 91.745 us; speedup vs baseline: 1.9348x; 1.9348x over previous
//
#include <hip/hip_runtime.h>
#include <math.h>

#define TPB 256
#define TILE 128          // target points staged per LDS tile
#define PPT 2             // source points per thread in k1

typedef float f32x2 __attribute__((ext_vector_type(2)));

// Kernel 1: partial min/max of pairwise squared distances, dot-product form,
// packed-fp32 (v_pk_fma_f32) over target pairs.
// dist(s,t) = |s|^2 + (|t|^2 - 2 s.t); min/max of a = |t|^2 - 2 s.t tracked,
// |s|^2 added in epilogue (monotone shift commutes with min/max).
// grid = (N/(PPT*TPB), S). Block (bx,s): 512 source points (2/thread) vs
// target chunk s, staged in LDS as SoA {x,y,z,|t|^2}.
// part layout: [S][N] float4 {min_start, max_start, min_end, max_end}
__global__ __launch_bounds__(TPB) void k1_partial_minmax(
    const float* __restrict__ source,
    const float* __restrict__ target,
    const float* __restrict__ trans_m,
    float4* __restrict__ part,
    int* __restrict__ counter,
    int N, int M, int T, int S)
{
    if (blockIdx.x == 0 && blockIdx.y == 0 && threadIdx.x == 0) *counter = 0;

    const int chunk = M / S;
    const int bx  = blockIdx.x;
    const int s   = blockIdx.y;
    const int tid = threadIdx.x;

    __shared__ f32x2 s_tx[TILE / 2], s_ty[TILE / 2], s_tz[TILE / 2], s_tw[TILE / 2];

    const int i0 = bx * (PPT * TPB) + tid;
    const int i1 = i0 + TPB;

    float sx0 = source[i0 * 3 + 0], sy0 = source[i0 * 3 + 1], sz0 = source[i0 * 3 + 2];
    float sx1 = source[i1 * 3 + 0], sy1 = source[i1 * 3 + 1], sz1 = source[i1 * 3 + 2];
    const long te = (long)(T - 1) * N * 3;
    const float ex0 = sx0 - trans_m[te + (long)i0 * 3 + 0];
    const float ey0 = sy0 - trans_m[te + (long)i0 * 3 + 1];
    const float ez0 = sz0 - trans_m[te + (long)i0 * 3 + 2];
    const float ex1 = sx1 - trans_m[te + (long)i1 * 3 + 0];
    const float ey1 = sy1 - trans_m[te + (long)i1 * 3 + 1];
    const float ez1 = sz1 - trans_m[te + (long)i1 * 3 + 2];

    const float ss0 = fmaf(sx0, sx0, fmaf(sy0, sy0, sz0 * sz0));
    const float ss1 = fmaf(sx1, sx1, fmaf(sy1, sy1, sz1 * sz1));
    const float ee0 = fmaf(ex0, ex0, fmaf(ey0, ey0, ez0 * ez0));
    const float ee1 = fmaf(ex1, ex1, fmaf(ey1, ey1, ez1 * ez1));

    // splatted -2*coords for the packed dot
    const f32x2 a0x = (f32x2)(-2.0f * sx0), a0y = (f32x2)(-2.0f * sy0), a0z = (f32x2)(-2.0f * sz0);
    const f32x2 a1x = (f32x2)(-2.0f * sx1), a1y = (f32x2)(-2.0f * sy1), a1z = (f32x2)(-2.0f * sz1);
    const f32x2 b0x = (f32x2)(-2.0f * ex0), b0y = (f32x2)(-2.0f * ey0), b0z = (f32x2)(-2.0f * ez0);
    const f32x2 b1x = (f32x2)(-2.0f * ex1), b1y = (f32x2)(-2.0f * ey1), b1z = (f32x2)(-2.0f * ez1);

    const f32x2 INF = (f32x2)(3.402823e38f), NINF = (f32x2)(-3.402823e38f);
    f32x2 mn_s0 = INF, mx_s0 = NINF, mn_e0 = INF, mx_e0 = NINF;
    f32x2 mn_s1 = INF, mx_s1 = NINF, mn_e1 = INF, mx_e1 = NINF;

    const int t_begin = s * chunk;
    const int t_end   = t_begin + chunk;

    for (int t0 = t_begin; t0 < t_end; t0 += TILE) {
        __syncthreads();
        if (tid < TILE) {
            const long j = (long)t0 + tid;
            const float tx = target[j * 3 + 0];
            const float ty = target[j * 3 + 1];
            const float tz = target[j * 3 + 2];
            ((float*)s_tx)[tid] = tx;
            ((float*)s_ty)[tid] = ty;
            ((float*)s_tz)[tid] = tz;
            ((float*)s_tw)[tid] = fmaf(tx, tx, fmaf(ty, ty, tz * tz));
        }
        __syncthreads();

        #pragma unroll 8
        for (int j2 = 0; j2 < TILE / 2; ++j2) {
            const f32x2 tx = s_tx[j2], ty = s_ty[j2], tz = s_tz[j2], tw = s_tw[j2];
            f32x2 a = a0x * tx + tw;  a = a0y * ty + a;  a = a0z * tz + a;
            mn_s0 = __builtin_elementwise_min(mn_s0, a);
            mx_s0 = __builtin_elementwise_max(mx_s0, a);
            f32x2 b = b0x * tx + tw;  b = b0y * ty + b;  b = b0z * tz + b;
            mn_e0 = __builtin_elementwise_min(mn_e0, b);
            mx_e0 = __builtin_elementwise_max(mx_e0, b);
            f32x2 c = a1x * tx + tw;  c = a1y * ty + c;  c = a1z * tz + c;
            mn_s1 = __builtin_elementwise_min(mn_s1, c);
            mx_s1 = __builtin_elementwise_max(mx_s1, c);
            f32x2 d = b1x * tx + tw;  d = b1y * ty + d;  d = b1z * tz + d;
            mn_e1 = __builtin_elementwise_min(mn_e1, d);
            mx_e1 = __builtin_elementwise_max(mx_e1, d);
        }
    }

    part[(long)s * N + i0] = make_float4(fminf(mn_s0.x, mn_s0.y) + ss0,
                                         fmaxf(mx_s0.x, mx_s0.y) + ss0,
                                         fminf(mn_e0.x, mn_e0.y) + ee0,
                                         fmaxf(mx_e0.x, mx_e0.y) + ee0);
    part[(long)s * N + i1] = make_float4(fminf(mn_s1.x, mn_s1.y) + ss1,
                                         fmaxf(mx_s1.x, mx_s1.y) + ss1,
                                         fminf(mn_e1.x, mn_e1.y) + ee1,
                                         fmaxf(mx_e1.x, mx_e1.y) + ee1);
}

// Kernel 2 (fused with final reduce): reduce partials per point, per-point
// loss + T-step scan, block-sum; last-done block sums block sums in fixed
// order (deterministic) and writes the mean.
__global__ __launch_bounds__(TPB) void k2_loss(
    const float4* __restrict__ part,
    const float* __restrict__ label,
    const float* __restrict__ path_m,
    const float* __restrict__ path_maxprob_m,
    float* __restrict__ blocksums,
    int* __restrict__ counter,
    float* __restrict__ out,
    int N, int S, int T)
{
    const int i = blockIdx.x * TPB + threadIdx.x;

    float mins = 3.402823e38f, maxs = -3.402823e38f;
    float mine = 3.402823e38f, maxe = -3.402823e38f;
    #pragma unroll 4
    for (int s = 0; s < S; ++s) {
        const float4 v = part[(long)s * N + i];
        mins = fminf(mins, v.x);
        maxs = fmaxf(maxs, v.y);
        mine = fminf(mine, v.z);
        maxe = fmaxf(maxe, v.w);
    }

    const float p = 0.002f, L0 = 0.4f, lam = 0.05f, gamma = 0.99f;
    const float loss_start = 0.99f * mins + 0.01f * maxs;
    const float loss_end   = 0.99f * mine + 0.01f * maxe;
    const float loss_dt    = loss_end - loss_start;
    const float d = fminf(loss_end / L0, 1.0f);
    const float l = expf(-label[i]);
    const float reward_end = -p * path_m[(long)(T - 1) * N + i]
                             - (d + lam * l) * loss_dt;

    float R = 0.0f, L = 0.0f;
    for (int t = T - 1; t >= 0; --t) {
        const float r  = (t == T - 1) ? reward_end
                                      : (-p * path_m[(long)t * N + i]);
        const float lp = logf(path_maxprob_m[(long)t * N + i]);
        R = gamma * R + lp * (r + 0.02f);
        L -= R;
    }
    float v = L / (float)T;

    for (int off = 32; off > 0; off >>= 1) v += __shfl_down(v, off, 64);
    __shared__ float red[TPB / 64];
    __shared__ bool amLast;
    const int wid = threadIdx.x >> 6, lane = threadIdx.x & 63;
    if (lane == 0) red[wid] = v;
    __syncthreads();
    if (threadIdx.x == 0) {
        float t = 0.0f;
        #pragma unroll
        for (int w = 0; w < TPB / 64; ++w) t += red[w];
        blocksums[blockIdx.x] = t;
        __threadfence();
        const int old = atomicAdd(counter, 1);
        amLast = (old == (int)gridDim.x - 1);
    }
    __syncthreads();
    if (amLast && threadIdx.x == 0) {
        __threadfence();
        float tot = 0.0f;
        for (int b = 0; b < (int)gridDim.x; ++b)
            tot += ((volatile float*)blocksums)[b];
        out[0] = tot / (float)N;
    }
}

extern "C" void kernel_launch(void* const* d_in, const int* in_sizes, int n_in,
                              void* d_out, int out_size, void* d_ws, size_t ws_size,
                              hipStream_t stream) {
    const float* source = (const float*)d_in[0];
    const float* target = (const float*)d_in[1];
    const float* label  = (const float*)d_in[2];
    const float* trans  = (const float*)d_in[3];
    const float* path   = (const float*)d_in[4];
    const float* pmax   = (const float*)d_in[5];

    const int N = in_sizes[0] / 3;          // 8192
    const int M = in_sizes[1] / 3;          // 8192
    const int T = in_sizes[3] / (N * 3);    // 8
    const int nbx1 = N / (PPT * TPB);       // 16
    const int nbx2 = N / TPB;               // 32

    // target-dim splits S (power of 2): partials fit d_ws, chunk multiple of TILE
    int S = 64;
    while (S > 1 && ((size_t)S * N * sizeof(float4)
                         + (size_t)(nbx2 + 1) * sizeof(float) > ws_size
                     || (M / S) < TILE))
        S >>= 1;

    float4* part     = (float4*)d_ws;                  // [S][N] float4
    float* blocksums = (float*)(part + (size_t)S * N); // [nbx2]
    int*   counter   = (int*)(blocksums + nbx2);       // [1]

    k1_partial_minmax<<<dim3(nbx1, S), TPB, 0, stream>>>(
        source, target, trans, part, counter, N, M, T, S);
    k2_loss<<<nbx2, TPB, 0, stream>>>(
        part, label, path, pmax, blocksums, counter, (float*)d_out, N, S, T);
}